// Round 3
// baseline (233.546 us; speedup 1.0000x reference)
//
#include <hip/hip_runtime.h>

// STDP learner: tr_pre/tr_post elementwise + delta_w = 0.5*w*(conv-wgrad pair).
// delta_w[o,i,kh,kw] = 0.5*w[o,i,kh,kw] *
//   sum_{b,p,q} tpre[b,i,p+kh,q+kw]*out[b,o,p,q] - tpost[b,o,p,q]*in[b,i,p+kh,q+kw]
// Sizes: B=16 CIN=64 H=W=66 COUT=128 HO=WO=64 KH=KW=3
// out layout: [tr_pre 4460544][tr_post 8388608][delta_w 73728]
//
// R8: barrier-free, LDS-free MFMA role (R7 post-mortem: 80% stall; per-stage
// __syncthreads forces vmcnt(0) drain of just-issued B loads => latency
// exposed every stage; 384 blocks -> 20% occupancy tail).
//  - A (out,tpost): global->reg per wave (o wave-partitioned, no reuse) as R7.
//  - B (tpre,in): each lane loads its OWN 10-float window (5x floatx2, 8B
//    aligned) from global per (nt,mat,ks); cvt_pk_bf16 + alignbit kw-shifts
//    in registers. Per-stage B footprint 33.8KB is L1/L2-hot; the 4x wave
//    redundancy is cache-served, cheaper than LDS+2 barriers/stage.
//  - Zero __syncthreads in the whole kernel; waves self-pipeline across
//    stages (compiler free to hoist next-stage loads; no vmcnt(0) cliffs).
//  - LDS=0 -> fill role no longer LDS-capped either.
//  - fill merged as before; partials + k_finalize epilogue unchanged.

typedef unsigned short ushort_t;
typedef unsigned int uint_t;
typedef __attribute__((ext_vector_type(8))) short short8;
typedef __attribute__((ext_vector_type(4))) float floatx4;
typedef __attribute__((ext_vector_type(2))) float floatx2;
typedef __attribute__((ext_vector_type(4))) int intx4;
typedef __attribute__((ext_vector_type(4))) uint_t uintx4;

#define N_POST   8388608     // 16*128*64*64
#define N_DW     73728       // 128*64*9
#define O_TRPOST 4460544
#define O_DW     12849152

#define MFMA_BLOCKS  384     // 3 kh * 128 (b,p0)
#define FILLA_BLOCKS 1024
#define FILLB_BLOCKS 768
#define TOTAL_BLOCKS 2176
#define B_ROWS_PER_WAVE 22   // 768*4*22 = 67584 rows exactly

// packed fp32->bf16, HW RNE (same rounding as bit-twiddle f2bf)
__device__ __forceinline__ int cvt2bf(float lo, float hi) {
  int r; asm("v_cvt_pk_bf16_f32 %0, %1, %2" : "=v"(r) : "v"(lo), "v"(hi)); return r;
}
__device__ __forceinline__ int cvt2bfn(float lo, float hi) {   // negated (free VOP3 mods)
  int r; asm("v_cvt_pk_bf16_f32 %0, -%1, -%2" : "=v"(r) : "v"(lo), "v"(hi)); return r;
}
// bytes [2..5] of (hi:lo) -- one v_alignbit_b32
__device__ __forceinline__ int bsh2(int hi, int lo) {
  return (int)((((unsigned long long)(uint_t)hi << 32) | (uint_t)lo) >> 16);
}

// ---- merged kernel ---------------------------------------------------------
// bx < 384:        MFMA role (needs ws for partials)
// 384..1408:       elementwise tr_post (float4 grid-stride, 8 iters exact)
// 1408..2176:      elementwise tr_pre (wave-per-row, lanes 0..32 x float2)
__global__ __launch_bounds__(256, 2)
void k_main(const float* __restrict__ in_sp, const float* __restrict__ out_sp,
            const float* __restrict__ tpre, const float* __restrict__ tpost,
            float* __restrict__ o_trpre, float* __restrict__ o_trpost,
            float* __restrict__ partials, int use_ws) {
  const int bx0 = blockIdx.x;
  const int t = threadIdx.x;

  if (bx0 >= MFMA_BLOCKS) {
    if (bx0 < MFMA_BLOCKS + FILLA_BLOCKS) {
      int i4 = (bx0 - MFMA_BLOCKS) * 256 + t;          // 2097152 = 262144*8
      #pragma unroll
      for (int it = 0; it < 8; ++it, i4 += FILLA_BLOCKS * 256) {
        floatx4 o = *(const floatx4*)(out_sp + i4 * 4);
        floatx4 p = *(const floatx4*)(tpost + i4 * 4);
        *(floatx4*)(o_trpost + i4 * 4) = 0.5f * p + o;
      }
    } else {
      const int l = t & 63;
      if (l >= 33) return;
      const int wid = (bx0 - (MFMA_BLOCKS + FILLA_BLOCKS)) * 4 + (t >> 6);
      #pragma unroll 2
      for (int it = 0; it < B_ROWS_PER_WAVE; ++it) {
        const int g = (wid * B_ROWS_PER_WAVE + it) * 66 + l * 2;
        floatx2 a = *(const floatx2*)(tpre + g);
        floatx2 c = *(const floatx2*)(in_sp + g);
        floatx2 v = { 0.5f * a.x + c.x, 0.5f * a.y + c.y };
        *(floatx2*)(o_trpre + g) = v;
      }
    }
    return;
  }
  if (!use_ws) return;                                 // fallback handles dw

  // ---- MFMA role: grid x -> kh = bx0>>7, bx = bx0&127 -> b = bx>>3, p0
  // block 256 = 4 waves, wave w owns o in [w*32, w*32+32). Per stage (p-row):
  //   A: 16x dwordx4 global->reg (16B aligned), cvt at use.
  //   B: per (nt,mat,ks): 5x dwordx2 (rows 8B aligned) -> cvt -> kw shifts.
  // No LDS, no barriers: waves independent, loads hoistable across stages.
  const int kh = bx0 >> 7, bx = bx0 & 127;
  const int b = bx >> 3, p0 = (bx & 7) * 8;
  const int w = t >> 6, l = t & 63;
  const int quad = l >> 4, l16 = l & 15;

  const float* arow0 = out_sp + ((b * 128 + w * 32 + l16) * 4096 + quad * 8 + p0 * 64);
  const float* arow1 = tpost  + ((b * 128 + w * 32 + l16) * 4096 + quad * 8 + p0 * 64);
  // B row base for this lane: row i = nt*16 + l16, col window quad*8 (+ks*32)
  const float* bbase0 = tpre  + ((b * 64 + l16) * 4356 + (p0 + kh) * 66 + quad * 8);
  const float* bbase1 = in_sp + ((b * 64 + l16) * 4356 + (p0 + kh) * 66 + quad * 8);

  floatx4 acc[3][2][4] = {};                           // [kw][mt][nt]

  for (int rr = 0; rr < 8; ++rr) {
    // A loads for this stage (issued first; ks=1 half covered by ks=0 compute)
    floatx4 ar[2][2][2][2];                            // [mat][mt][ks][half]
    #pragma unroll
    for (int mt = 0; mt < 2; ++mt)
      #pragma unroll
      for (int ks = 0; ks < 2; ++ks)
        #pragma unroll
        for (int hf = 0; hf < 2; ++hf) {
          const int off = rr * 64 + mt * 65536 + ks * 32 + hf * 4;
          ar[0][mt][ks][hf] = *(const floatx4*)(arow0 + off);
          ar[1][mt][ks][hf] = *(const floatx4*)(arow1 + off);
        }

    #pragma unroll
    for (int ks = 0; ks < 2; ++ks) {
      short8 fa[2][2];                                 // [mat][mt]
      #pragma unroll
      for (int mt = 0; mt < 2; ++mt) {
        uintx4 ua = { (uint_t)cvt2bf (ar[0][mt][ks][0].x, ar[0][mt][ks][0].y),
                      (uint_t)cvt2bf (ar[0][mt][ks][0].z, ar[0][mt][ks][0].w),
                      (uint_t)cvt2bf (ar[0][mt][ks][1].x, ar[0][mt][ks][1].y),
                      (uint_t)cvt2bf (ar[0][mt][ks][1].z, ar[0][mt][ks][1].w) };
        uintx4 un = { (uint_t)cvt2bfn(ar[1][mt][ks][0].x, ar[1][mt][ks][0].y),
                      (uint_t)cvt2bfn(ar[1][mt][ks][0].z, ar[1][mt][ks][0].w),
                      (uint_t)cvt2bfn(ar[1][mt][ks][1].x, ar[1][mt][ks][1].y),
                      (uint_t)cvt2bfn(ar[1][mt][ks][1].z, ar[1][mt][ks][1].w) };
        fa[0][mt] = __builtin_bit_cast(short8, ua);    // A1 = out
        fa[1][mt] = __builtin_bit_cast(short8, un);    // A2 = -tpost
      }
      #pragma unroll
      for (int nt = 0; nt < 4; ++nt) {
        // B window: rows nt*16+l16 (both mats), elems [ks*32+quad*8 .. +10)
        const int boff = rr * 66 + nt * 69696 + ks * 32;
        const float* r0 = bbase0 + boff;
        const float* r1 = bbase1 + boff;
        floatx2 q0[5], q1[5];
        #pragma unroll
        for (int k2 = 0; k2 < 5; ++k2) {
          q0[k2] = *(const floatx2*)(r0 + 2 * k2);
          q1[k2] = *(const floatx2*)(r1 + 2 * k2);
        }
        int c0[5], c1[5];
        #pragma unroll
        for (int k2 = 0; k2 < 5; ++k2) {
          c0[k2] = cvt2bf(q0[k2].x, q0[k2].y);
          c1[k2] = cvt2bf(q1[k2].x, q1[k2].y);
        }
        short8 fb[2][3];                               // [mat][kw]
        {
          intx4 f00 = { c0[0], c0[1], c0[2], c0[3] };
          intx4 f01 = { bsh2(c0[1], c0[0]), bsh2(c0[2], c0[1]),
                        bsh2(c0[3], c0[2]), bsh2(c0[4], c0[3]) };
          intx4 f02 = { c0[1], c0[2], c0[3], c0[4] };
          intx4 f10 = { c1[0], c1[1], c1[2], c1[3] };
          intx4 f11 = { bsh2(c1[1], c1[0]), bsh2(c1[2], c1[1]),
                        bsh2(c1[3], c1[2]), bsh2(c1[4], c1[3]) };
          intx4 f12 = { c1[1], c1[2], c1[3], c1[4] };
          fb[0][0] = __builtin_bit_cast(short8, f00);
          fb[0][1] = __builtin_bit_cast(short8, f01);
          fb[0][2] = __builtin_bit_cast(short8, f02);
          fb[1][0] = __builtin_bit_cast(short8, f10);
          fb[1][1] = __builtin_bit_cast(short8, f11);
          fb[1][2] = __builtin_bit_cast(short8, f12);
        }
        #pragma unroll
        for (int kw = 0; kw < 3; ++kw)
          #pragma unroll
          for (int mt = 0; mt < 2; ++mt) {
            acc[kw][mt][nt] = __builtin_amdgcn_mfma_f32_16x16x32_bf16(fa[0][mt], fb[0][kw], acc[kw][mt][nt], 0, 0, 0);
            acc[kw][mt][nt] = __builtin_amdgcn_mfma_f32_16x16x32_bf16(fa[1][mt], fb[1][kw], acc[kw][mt][nt], 0, 0, 0);
          }
      }
    }
  }

  // C/D layout: col(i)=lane&15, row(o within 16)=quad*4+reg (HW-verified)
  #pragma unroll
  for (int kw = 0; kw < 3; ++kw) {
    float* slice = partials + (size_t)((kh * 3 + kw) * 128 + bx) * 8192;
    #pragma unroll
    for (int mt = 0; mt < 2; ++mt)
      #pragma unroll
      for (int nt = 0; nt < 4; ++nt)
        #pragma unroll
        for (int rg = 0; rg < 4; ++rg) {
          const int o = w * 32 + mt * 16 + quad * 4 + rg;
          const int i = nt * 16 + l16;
          slice[o * 64 + i] = acc[kw][mt][nt][rg];
        }
  }
}

// ---- split-K reduction + finalize ------------------------------------------
__global__ void k_finalize(const float* __restrict__ partials,
                           const float* __restrict__ weight, float* __restrict__ dw) {
  int tid = blockIdx.x * 256 + threadIdx.x;            // < 73728
  int e = tid >> 13, oi = tid & 8191;
  float s = 0.f;
  #pragma unroll 8
  for (int c = 0; c < 128; ++c) s += partials[(size_t)(e * 128 + c) * 8192 + oi];
  int o = oi >> 6, i = oi & 63;
  int wi = (o * 64 + i) * 9 + e;
  dw[wi] = 0.5f * weight[wi] * s;
}

// ---- fallback (ws too small): slow fp32, zero scratch ----------------------
__global__ void k_naive(const float* __restrict__ out_sp, const float* __restrict__ tpost,
                        const float* __restrict__ tpre, const float* __restrict__ in_sp,
                        const float* __restrict__ weight, float* __restrict__ dw) {
  int tid = blockIdx.x * 256 + threadIdx.x;
  int e = tid >> 13, oi = tid & 8191;
  int o = oi >> 6, i = oi & 63;
  int kh = e / 3, kw = e - kh * 3;
  float acc = 0.f;
  for (int b = 0; b < 16; ++b)
    for (int p = 0; p < 64; ++p) {
      const float* ga = out_sp + ((b * 128 + o) * 64 + p) * 64;
      const float* gn = tpost + ((b * 128 + o) * 64 + p) * 64;
      const float* gb = tpre + ((b * 64 + i) * 66 + p + kh) * 66 + kw;
      const float* gm = in_sp + ((b * 64 + i) * 66 + p + kh) * 66 + kw;
      for (int q = 0; q < 64; ++q) acc += ga[q] * gb[q] - gn[q] * gm[q];
    }
  int wi = (o * 64 + i) * 9 + kh * 3 + kw;
  dw[wi] = 0.5f * weight[wi] * acc;
}

extern "C" void kernel_launch(void* const* d_in, const int* in_sizes, int n_in,
                              void* d_out, int out_size, void* d_ws, size_t ws_size,
                              hipStream_t stream) {
  const float* in_sp  = (const float*)d_in[0];
  const float* out_sp = (const float*)d_in[1];
  const float* tpre   = (const float*)d_in[2];
  const float* tpost  = (const float*)d_in[3];
  const float* weight = (const float*)d_in[4];
  float* out = (float*)d_out;
  float* o_trpre  = out;
  float* o_trpost = out + O_TRPOST;
  float* o_dw     = out + O_DW;

  // ws: partials only (9*128*8192 fp32 = 37.7MB)
  const size_t WS_NEED = (size_t)9 * 128 * 8192 * 4;
  const int use_mfma = (ws_size >= WS_NEED) ? 1 : 0;
  float* partials = (float*)d_ws;

  k_main<<<TOTAL_BLOCKS, 256, 0, stream>>>(in_sp, out_sp, tpre, tpost,
                                           o_trpre, o_trpost, partials, use_mfma);
  if (use_mfma) {
    k_finalize<<<N_DW / 256, 256, 0, stream>>>(partials, weight, o_dw);
  } else {
    k_naive<<<N_DW / 256, 256, 0, stream>>>(out_sp, tpost, tpre, in_sp, weight, o_dw);
  }
}